// Round 20
// baseline (330.200 us; speedup 1.0000x reference)
//
#include <hip/hip_runtime.h>

typedef __attribute__((ext_vector_type(8))) short s8v;
typedef __attribute__((ext_vector_type(4))) float f4v;

#define PADG 72

union U8 { unsigned u[4]; s8v s; };

__device__ __forceinline__ void gload16(const void* g, void* l) {
  __builtin_amdgcn_global_load_lds((const __attribute__((address_space(1))) void*)g,
                                   (__attribute__((address_space(3))) void*)l, 16, 0, 0);
}

__device__ __forceinline__ unsigned short f2bf(float f) {
  unsigned u = __float_as_uint(f);
  u += 0x7fffu + ((u >> 16) & 1u);
  return (unsigned short)(u >> 16);
}
__device__ __forceinline__ unsigned short f2bfc(float f) {
  return (unsigned short)((__float_as_uint(f) + 0x8000u) >> 16);
}
__device__ __forceinline__ float bf2f(unsigned short h) {
  return __uint_as_float(((unsigned)h) << 16);
}
__device__ __forceinline__ float rdlanef(float v, int l) {
  return __uint_as_float(__builtin_amdgcn_readlane(__float_as_uint(v), l));
}
__device__ __forceinline__ void split2(float x0, float x1, unsigned& hp, unsigned& lp) {
  unsigned t0 = __float_as_uint(x0) + 0x8000u;
  unsigned t1 = __float_as_uint(x1) + 0x8000u;
  float h0 = __uint_as_float(t0 & 0xFFFF0000u);
  float h1 = __uint_as_float(t1 & 0xFFFF0000u);
  float l0 = x0 - h0, l1 = x1 - h1;
  hp = __builtin_amdgcn_perm(t1, t0, 0x07060302u);
  lp = __builtin_amdgcn_perm(__float_as_uint(l1) + 0x8000u,
                             __float_as_uint(l0) + 0x8000u, 0x07060302u);
}
__device__ __forceinline__ unsigned pack2(float a, float b) {
  return __builtin_amdgcn_perm(__float_as_uint(b) + 0x8000u,
                               __float_as_uint(a) + 0x8000u, 0x07060302u);
}
__device__ __forceinline__ f4v vmax4(f4v a, f4v b) {
  f4v r; r[0]=fmaxf(a[0],b[0]); r[1]=fmaxf(a[1],b[1]); r[2]=fmaxf(a[2],b[2]); r[3]=fmaxf(a[3],b[3]); return r;
}
__device__ __forceinline__ f4v shflxor4(f4v v, int m) {
  f4v r; r[0]=__shfl_xor(v[0],m); r[1]=__shfl_xor(v[1],m); r[2]=__shfl_xor(v[2],m); r[3]=__shfl_xor(v[3],m); return r;
}
__device__ __forceinline__ f4v exp4(f4v v) {
  f4v r; r[0]=__expf(v[0]); r[1]=__expf(v[1]); r[2]=__expf(v[2]); r[3]=__expf(v[3]); return r;
}

// ---------------- prep ----------------
__global__ void k_prep(const float* __restrict__ W_in, const float* __restrict__ lnis,
                       const float* __restrict__ lnib, const float* __restrict__ W_out,
                       const float* __restrict__ skeys, const float* __restrict__ smem0,
                       const float* __restrict__ wgate,
                       unsigned short* __restrict__ wth, unsigned short* __restrict__ wtl,
                       unsigned short* __restrict__ wot, float* __restrict__ keyn,
                       float* __restrict__ d0, float* __restrict__ uvec, float* __restrict__ vvec)
{
  __shared__ float pr[4];
  const int bid = blockIdx.x, tid = threadIdx.x;
  if (bid < 1024) {
    int idx = bid * 256 + tid;           // wt layout [n=256][k=1024]
    int n = idx >> 10, k = idx & 1023;
    float val = lnis[k] * W_in[k * 256 + n];
    unsigned short h = f2bf(val);
    wth[idx] = h;
    wtl[idx] = f2bf(val - bf2f(h));
  } else if (bid < 2048) {
    int idx = (bid - 1024) * 256 + tid;  // wot layout [n=1024][k=256]
    int n = idx >> 8, k = idx & 255;
    wot[idx] = f2bf(W_out[k * 1024 + n]);
  } else if (bid == 2048) {
    float su = 0.f, sv = 0.f;
    for (int i = 0; i < 1024; ++i) {
      float wv_ = W_in[i * 256 + tid];
      su += lnis[i] * wv_;
      sv += lnib[i] * wv_;
    }
    uvec[tid] = su; vvec[tid] = sv;
  } else {
    int n = bid - 2049;
    float sk = skeys[n * 256 + tid];
    float sq = sk * sk;
    #pragma unroll
    for (int m = 32; m; m >>= 1) sq += __shfl_xor(sq, m);
    if ((tid & 63) == 0) pr[tid >> 6] = sq;
    __syncthreads();
    float tot = pr[0] + pr[1] + pr[2] + pr[3];
    keyn[n * 256 + tid] = sk * (1.0f / fmaxf(sqrtf(tot), 1e-12f));
    float pd = smem0[n * 256 + tid] * wgate[tid];
    #pragma unroll
    for (int m = 32; m; m >>= 1) pd += __shfl_xor(pd, m);
    __syncthreads();
    if ((tid & 63) == 0) pr[tid >> 6] = pd;
    __syncthreads();
    if (tid == 0) d0[n] = pr[0] + pr[1] + pr[2] + pr[3];
  }
}

// ---------------- GEMM1: XCD-aware mapping, split-bf16 ----------------
__global__ __launch_bounds__(512, 4) void k_gemm1(const float* __restrict__ x,
    const unsigned short* __restrict__ wth, const unsigned short* __restrict__ wtl,
    const float* __restrict__ uvec, const float* __restrict__ vvec,
    float* __restrict__ q)
{
  __shared__ unsigned short Ah[128 * PADG], Al[128 * PADG];
  __shared__ unsigned short Bh[128 * PADG], Bl[128 * PADG];
  __shared__ float uls[128], vls[128];
  __shared__ float mls[128], rls[128];
  const int tid = threadIdx.x;
  const int w = tid >> 6, lane = tid & 63;
  const int wm = w >> 2, wn = w & 3;
  const int bid = blockIdx.x;
  const int mblk = (bid >> 4) * 8 + (bid & 7), nblk = (bid >> 3) & 1;
  const int row0 = mblk * 128, n0 = nblk * 128;
  if (tid < 128) { uls[tid] = uvec[n0 + tid]; vls[tid] = vvec[n0 + tid]; }
  f4v zz = {0.f, 0.f, 0.f, 0.f};
  f4v acc[4][2];
  #pragma unroll
  for (int i = 0; i < 4; ++i)
    #pragma unroll
    for (int j = 0; j < 2; ++j) acc[i][j] = zz;
  const int rowA = tid >> 2, kqA = (tid & 3) * 16;
  float ps = 0.f, pss = 0.f;
  for (int kt = 0; kt < 16; ++kt) {
    const int k0 = kt * 64;
    {
      const float* src = x + (size_t)(row0 + rowA) * 1024 + k0 + kqA;
      float vv[16];
      #pragma unroll
      for (int i = 0; i < 4; ++i) *(f4v*)(vv + 4 * i) = *(const f4v*)(src + 4 * i);
      unsigned hp[8], lp[8];
      #pragma unroll
      for (int i = 0; i < 8; ++i) {
        ps += vv[2 * i] + vv[2 * i + 1];
        pss += vv[2 * i] * vv[2 * i] + vv[2 * i + 1] * vv[2 * i + 1];
        split2(vv[2 * i], vv[2 * i + 1], hp[i], lp[i]);
      }
      uint4* dh = (uint4*)&Ah[rowA * PADG + kqA];
      uint4* dl = (uint4*)&Al[rowA * PADG + kqA];
      dh[0] = make_uint4(hp[0], hp[1], hp[2], hp[3]);
      dh[1] = make_uint4(hp[4], hp[5], hp[6], hp[7]);
      dl[0] = make_uint4(lp[0], lp[1], lp[2], lp[3]);
      dl[1] = make_uint4(lp[4], lp[5], lp[6], lp[7]);
      const unsigned short* sh = wth + (size_t)(n0 + rowA) * 1024 + k0 + kqA;
      const unsigned short* sl = wtl + (size_t)(n0 + rowA) * 1024 + k0 + kqA;
      *(s8v*)&Bh[rowA * PADG + kqA] = *(const s8v*)sh;
      *(s8v*)&Bh[rowA * PADG + kqA + 8] = *(const s8v*)(sh + 8);
      *(s8v*)&Bl[rowA * PADG + kqA] = *(const s8v*)sl;
      *(s8v*)&Bl[rowA * PADG + kqA + 8] = *(const s8v*)(sl + 8);
    }
    __syncthreads();
    #pragma unroll
    for (int kk = 0; kk < 64; kk += 32) {
      const int kb = kk + (lane >> 4) * 8;
      s8v ah[4], al[4], bh[2], bl[2];
      #pragma unroll
      for (int mi = 0; mi < 4; ++mi) {
        const int rr = (wm * 64 + mi * 16 + (lane & 15)) * PADG + kb;
        ah[mi] = *(const s8v*)&Ah[rr];
        al[mi] = *(const s8v*)&Al[rr];
      }
      #pragma unroll
      for (int ni = 0; ni < 2; ++ni) {
        const int ccv = (wn * 32 + ni * 16 + (lane & 15)) * PADG + kb;
        bh[ni] = *(const s8v*)&Bh[ccv];
        bl[ni] = *(const s8v*)&Bl[ccv];
      }
      #pragma unroll
      for (int mi = 0; mi < 4; ++mi)
        #pragma unroll
        for (int ni = 0; ni < 2; ++ni) {
          acc[mi][ni] = __builtin_amdgcn_mfma_f32_16x16x32_bf16(ah[mi], bh[ni], acc[mi][ni], 0, 0, 0);
          acc[mi][ni] = __builtin_amdgcn_mfma_f32_16x16x32_bf16(ah[mi], bl[ni], acc[mi][ni], 0, 0, 0);
          acc[mi][ni] = __builtin_amdgcn_mfma_f32_16x16x32_bf16(al[mi], bh[ni], acc[mi][ni], 0, 0, 0);
        }
    }
    __syncthreads();
  }
  {
    float s0 = ps, s1 = pss;
    s0 += __shfl_xor(s0, 1); s1 += __shfl_xor(s1, 1);
    s0 += __shfl_xor(s0, 2); s1 += __shfl_xor(s1, 2);
    if ((tid & 3) == 0) {
      float mean = s0 * (1.0f / 1024.0f);
      mls[rowA] = mean;
      rls[rowA] = rsqrtf(s1 * (1.0f / 1024.0f) - mean * mean + 1e-5f);
    }
  }
  __syncthreads();
  #pragma unroll
  for (int mi = 0; mi < 4; ++mi)
    #pragma unroll
    for (int j = 0; j < 4; ++j) {
      const int lr = wm * 64 + mi * 16 + (lane >> 4) * 4 + j;
      const int r = row0 + lr;
      const float mv = mls[lr], rv = rls[lr];
      #pragma unroll
      for (int ni = 0; ni < 2; ++ni) {
        const int lc = wn * 32 + ni * 16 + (lane & 15);
        q[(size_t)r * 256 + n0 + lc] = rv * acc[mi][ni][j] - rv * mv * uls[lc] + vls[lc];
      }
    }
}

// ---------------- attention: Kf f32 + bf16 P (80KB LDS exactly -> 2 blocks/CU), 4 chunks/block ----------------
__global__ __launch_bounds__(512, 4) void k_attn(const float* __restrict__ q,
    const float* __restrict__ smem0, unsigned short* __restrict__ readb,
    float* __restrict__ summ)
{
  __shared__ float Kf[64 * 256];              // 65536 B
  __shared__ unsigned short Plb[8][16 * 64];  // 16384 B  -> total 81920 B = 80 KB
  const int tid = threadIdx.x;
  const int w = tid >> 6, lane = tid & 63;
  const int cl = w >> 2, h = w & 3;
  const int l15 = lane & 15, kq = lane >> 4;

  {
    const int base = tid * 32;
    #pragma unroll
    for (int i = 0; i < 8; ++i)
      *(f4v*)&Kf[base + i * 4] = *(const f4v*)&smem0[base + i * 4];
  }
  __syncthreads();

  s8v bsh[4][2], bsl[4][2], bpv[4][2];
  #pragma unroll
  for (int nt = 0; nt < 4; ++nt)
    #pragma unroll
    for (int ks = 0; ks < 2; ++ks) {
      const float* src = &Kf[(nt * 16 + l15) * 256 + h * 64 + ks * 32 + kq * 8];
      float tmp[8];
      *(f4v*)tmp = *(const f4v*)src; *(f4v*)(tmp + 4) = *(const f4v*)(src + 4);
      U8 uh, ul;
      #pragma unroll
      for (int j = 0; j < 4; ++j) split2(tmp[2 * j], tmp[2 * j + 1], uh.u[j], ul.u[j]);
      bsh[nt][ks] = uh.s;
      bsl[nt][ks] = ul.s;
      U8 up;
      #pragma unroll
      for (int j = 0; j < 4; ++j)
        up.u[j] = pack2(Kf[(ks * 32 + kq * 8 + 2 * j) * 256 + h * 64 + nt * 16 + l15],
                        Kf[(ks * 32 + kq * 8 + 2 * j + 1) * 256 + h * 64 + nt * 16 + l15]);
      bpv[nt][ks] = up.s;
    }

  const int g0 = blockIdx.x * 4 + cl * 2;
  f4v qv[2][4];
  #pragma unroll
  for (int i = 0; i < 2; ++i)
    #pragma unroll
    for (int ks = 0; ks < 2; ++ks) {
      const float* qp = q + (size_t)((g0 + i) * 16 + l15) * 256 + h * 64 + ks * 32 + kq * 8;
      qv[i][ks * 2] = *(const f4v*)qp;
      qv[i][ks * 2 + 1] = *(const f4v*)(qp + 4);
    }
  #pragma unroll
  for (int i = 0; i < 2; ++i) {
    const int g = g0 + i;
    s8v ah[2], al[2];
    #pragma unroll
    for (int ks = 0; ks < 2; ++ks) {
      float tmp[8];
      *(f4v*)tmp = qv[i][ks * 2]; *(f4v*)(tmp + 4) = qv[i][ks * 2 + 1];
      U8 uh, ul;
      #pragma unroll
      for (int j = 0; j < 4; ++j) split2(tmp[2 * j], tmp[2 * j + 1], uh.u[j], ul.u[j]);
      ah[ks] = uh.s; al[ks] = ul.s;
    }
    f4v zz = {0.f, 0.f, 0.f, 0.f};
    f4v sacc[4] = {zz, zz, zz, zz};
    #pragma unroll
    for (int ks = 0; ks < 2; ++ks)
      #pragma unroll
      for (int nt = 0; nt < 4; ++nt) {
        sacc[nt] = __builtin_amdgcn_mfma_f32_16x16x32_bf16(ah[ks], bsh[nt][ks], sacc[nt], 0, 0, 0);
        sacc[nt] = __builtin_amdgcn_mfma_f32_16x16x32_bf16(ah[ks], bsl[nt][ks], sacc[nt], 0, 0, 0);
        sacc[nt] = __builtin_amdgcn_mfma_f32_16x16x32_bf16(al[ks], bsh[nt][ks], sacc[nt], 0, 0, 0);
      }
    #pragma unroll
    for (int nt = 0; nt < 4; ++nt) sacc[nt] = sacc[nt] * 0.125f;
    f4v mx = vmax4(vmax4(sacc[0], sacc[1]), vmax4(sacc[2], sacc[3]));
    #pragma unroll
    for (int m = 1; m <= 8; m <<= 1) mx = vmax4(mx, shflxor4(mx, m));
    f4v p[4];
    f4v psum = zz;
    #pragma unroll
    for (int nt = 0; nt < 4; ++nt) { p[nt] = exp4(sacc[nt] - mx); psum = psum + p[nt]; }
    #pragma unroll
    for (int m = 1; m <= 8; m <<= 1) psum = psum + shflxor4(psum, m);
    f4v rs;
    rs[0] = 1.0f / psum[0]; rs[1] = 1.0f / psum[1];
    rs[2] = 1.0f / psum[2]; rs[3] = 1.0f / psum[3];
    #pragma unroll
    for (int nt = 0; nt < 4; ++nt) p[nt] = p[nt] * rs;
    float cs4[4];
    #pragma unroll
    for (int nt = 0; nt < 4; ++nt) {
      cs4[nt] = p[nt][0] + p[nt][1] + p[nt][2] + p[nt][3];
      cs4[nt] += __shfl_xor(cs4[nt], 16);
      cs4[nt] += __shfl_xor(cs4[nt], 32);
    }
    // P -> bf16 LDS (rounding here == old pack2-at-read; bit-identical pa)
    #pragma unroll
    for (int nt = 0; nt < 4; ++nt)
      #pragma unroll
      for (int j = 0; j < 4; ++j)
        Plb[w][(kq * 4 + j) * 64 + nt * 16 + l15] = f2bfc(p[nt][j]);
    s8v pa[2];
    #pragma unroll
    for (int ks = 0; ks < 2; ++ks)
      pa[ks] = *(const s8v*)&Plb[w][l15 * 64 + ks * 32 + kq * 8];
    f4v racc[4] = {zz, zz, zz, zz};
    #pragma unroll
    for (int ks = 0; ks < 2; ++ks)
      #pragma unroll
      for (int nt = 0; nt < 4; ++nt)
        racc[nt] = __builtin_amdgcn_mfma_f32_16x16x32_bf16(pa[ks], bpv[nt][ks], racc[nt], 0, 0, 0);
    const int rowbase = (g >> 8) * 4096 + (g & 255) * 16;
    #pragma unroll
    for (int nt = 0; nt < 4; ++nt)
      #pragma unroll
      for (int j = 0; j < 4; ++j)
        readb[(size_t)(rowbase + kq * 4 + j) * 256 + h * 64 + nt * 16 + l15] = f2bfc(racc[nt][j]);
    // exact summary: readlane broadcasts of colsums (no csm LDS)
    float s = 0.f;
    #pragma unroll
    for (int nt = 0; nt < 4; ++nt)
      #pragma unroll
      for (int j = 0; j < 16; ++j)
        s = fmaf(rdlanef(cs4[nt], j), Kf[(nt * 16 + j) * 256 + h * 64 + lane], s);
    summ[(size_t)g * 256 + h * 64 + lane] = s * (1.0f / 16.0f);
  }
}

// ---------------- per-chunk: 8 chunks/block ----------------
__global__ void k_match(const float* __restrict__ summ, const float* __restrict__ keyn,
                        const float* __restrict__ Wwr, const float* __restrict__ wgate,
                        int* __restrict__ top3, float* __restrict__ wv,
                        float* __restrict__ wg2, float* __restrict__ dwv)
{
  __shared__ float sm[8][256];
  __shared__ float nrm_inv[8];
  __shared__ float mtch[8][64];
  __shared__ float redA[8][4], redB[8][4];
  const int tid = threadIdx.x, lane = tid & 63, w = tid >> 6;
  const int gbase = blockIdx.x * 8;
  #pragma unroll
  for (int gi = 0; gi < 8; ++gi) sm[gi][tid] = summ[(size_t)(gbase + gi) * 256 + tid];
  __syncthreads();
  {
    #pragma unroll
    for (int pass = 0; pass < 2; ++pass) {
      const int gi = w + pass * 4;
      float ss = 0.f;
      #pragma unroll
      for (int i = 0; i < 4; ++i) { float vv_ = sm[gi][lane + i * 64]; ss += vv_ * vv_; }
      #pragma unroll
      for (int m = 32; m; m >>= 1) ss += __shfl_xor(ss, m);
      if (lane == 0) nrm_inv[gi] = 1.0f / fmaxf(sqrtf(ss), 1e-12f);
    }
  }
  __syncthreads();
  {
    const int n = tid >> 2, qq = tid & 3;
    float mac[8] = {0.f, 0.f, 0.f, 0.f, 0.f, 0.f, 0.f, 0.f};
    const float* kp = keyn + n * 256 + qq * 64;
    for (int d = 0; d < 64; ++d) {
      float kv = kp[d];
      int dd = qq * 64 + d;
      #pragma unroll
      for (int gi = 0; gi < 8; ++gi) mac[gi] += sm[gi][dd] * kv;
    }
    #pragma unroll
    for (int gi = 0; gi < 8; ++gi) {
      float v2_ = mac[gi];
      v2_ += __shfl_xor(v2_, 1);
      v2_ += __shfl_xor(v2_, 2);
      if (qq == 0) mtch[gi][n] = v2_ * nrm_inv[gi];
    }
  }
  __syncthreads();
  {
    #pragma unroll
    for (int pass = 0; pass < 2; ++pass) {
      const int gi = w + pass * 4;
      float vorig = mtch[gi][lane];
      #pragma unroll
      for (int it = 0; it < 3; ++it) {
        float rv = vorig; int ri = lane;
        #pragma unroll
        for (int m = 32; m; m >>= 1) {
          float ov = __shfl_xor(rv, m); int oi = __shfl_xor(ri, m);
          if (ov > rv || (ov == rv && oi < ri)) { rv = ov; ri = oi; }
        }
        if (lane == 0) top3[(gbase + gi) * 4 + it] = ri;
        if (lane == ri) vorig = -3.0e38f;
      }
    }
  }
  float wva[8] = {0.f, 0.f, 0.f, 0.f, 0.f, 0.f, 0.f, 0.f};
  for (int d = 0; d < 256; ++d) {
    float ww = Wwr[(size_t)d * 256 + tid];
    #pragma unroll
    for (int gi = 0; gi < 8; ++gi) wva[gi] += sm[gi][d] * ww;
  }
  const float g1 = wgate[tid], g2 = wgate[256 + tid];
  #pragma unroll
  for (int gi = 0; gi < 8; ++gi) {
    wv[(size_t)(gbase + gi) * 256 + tid] = wva[gi];
    float p2 = wva[gi] * g2, p1 = wva[gi] * g1;
    #pragma unroll
    for (int m = 32; m; m >>= 1) { p2 += __shfl_xor(p2, m); p1 += __shfl_xor(p1, m); }
    if (lane == 0) { redA[gi][w] = p2; redB[gi][w] = p1; }
  }
  __syncthreads();
  if (tid < 8) {
    wg2[gbase + tid] = redA[tid][0] + redA[tid][1] + redA[tid][2] + redA[tid][3];
    dwv[gbase + tid] = redB[tid][0] + redB[tid][1] + redB[tid][2] + redB[tid][3];
  }
}

// ---------------- scan: single-lane LDS-resident gate chain ----------------
__global__ __launch_bounds__(1024) void k_scan(const float* __restrict__ d0,
    const int* __restrict__ top3, const float* __restrict__ wg2, const float* __restrict__ dwv,
    const float* __restrict__ bgate, const float* __restrict__ wv,
    const float* __restrict__ smem0, const float* __restrict__ lnss,
    const float* __restrict__ lnsb, float* __restrict__ outns)
{
  __shared__ float Wl[256][64];
  __shared__ float pn[64];
  __shared__ float wvs[32][256];
  __shared__ float gls[256];
  __shared__ int   pprm[256][4];
  __shared__ float dsl[64];
  const int bb = blockIdx.x, tid = threadIdx.x;
  const int lane = tid & 63;

  int ixA[4], iyA[4], izA[4];
  if (tid < 64) {
    const float bg = bgate[0];
    const float L2E = 1.4426950408889634f;
    #pragma unroll
    for (int j = 0; j < 4; ++j) {
      const int c = j * 64 + tid;
      int4 t3 = *(const int4*)&top3[(bb * 256 + c) * 4];
      ixA[j] = t3.x; iyA[j] = t3.y; izA[j] = t3.z;
      pprm[c][0] = t3.x | (t3.y << 6) | (t3.z << 12);
      pprm[c][1] = __float_as_int(-(wg2[bb * 256 + c] + bg) * L2E);
      pprm[c][2] = __float_as_int(dwv[bb * 256 + c]);
      pprm[c][3] = 0;
    }
    dsl[tid] = d0[tid];
  }
  __syncthreads();

  if (tid == 0) {
    const float COEFN = -0.48089834696298783f;
    #pragma unroll 2
    for (int c = 0; c < 256; ++c) {
      const int4 pr = *(const int4*)&pprm[c][0];
      const int i0 = pr.x & 63, i1 = (pr.x >> 6) & 63, i2 = (pr.x >> 12) & 63;
      const float wz = __int_as_float(pr.y);
      const float dv = __int_as_float(pr.z);
      const float a = dsl[i0], b = dsl[i1], d2 = dsl[i2];
      const float s3 = a + b + d2;
      const float e = __builtin_amdgcn_exp2f(fmaf(s3, COEFN, wz));
      const float g = __builtin_amdgcn_rcpf(1.0f + e);
      gls[c] = g;
      dsl[i0] = fmaf(g, dv - a, a);
      dsl[i1] = fmaf(g, dv - b, b);
      dsl[i2] = fmaf(g, dv - d2, d2);
    }
  }
  __syncthreads();

  if (tid < 64) {
    float running = 1.0f;
    #pragma unroll
    for (int j = 3; j >= 0; --j) {
      #pragma unroll 1
      for (int sl = 63; sl >= 0; --sl) {
        const int a0 = __builtin_amdgcn_readlane(ixA[j], sl);
        const int a1 = __builtin_amdgcn_readlane(iyA[j], sl);
        const int a2 = __builtin_amdgcn_readlane(izA[j], sl);
        const float gv = gls[j * 64 + sl];
        const bool hit = (lane == a0) | (lane == a1) | (lane == a2);
        Wl[j * 64 + sl][lane] = hit ? gv * running : 0.f;
        running = hit ? running * (1.0f - gv) : running;
      }
    }
    pn[lane] = running;
  }
  __syncthreads();

  const int n = tid >> 4, dq = tid & 15;
  float acc[16];
  {
    const float p = pn[n];
    const float* v0p = smem0 + n * 256 + dq * 16;
    #pragma unroll
    for (int i = 0; i < 16; i += 4) {
      f4v v0 = *(const f4v*)(v0p + i);
      acc[i] = p * v0[0]; acc[i + 1] = p * v0[1];
      acc[i + 2] = p * v0[2]; acc[i + 3] = p * v0[3];
    }
  }
  const int rr = tid >> 5, cc8 = (tid & 31) * 8;
  for (int ct = 0; ct < 8; ++ct) {
    __syncthreads();
    {
      const float* src = wv + (size_t)(bb * 256 + ct * 32 + rr) * 256 + cc8;
      *(f4v*)&wvs[rr][cc8] = *(const f4v*)src;
      *(f4v*)&wvs[rr][cc8 + 4] = *(const f4v*)(src + 4);
    }
    __syncthreads();
    #pragma unroll 1
    for (int cc = 0; cc < 32; ++cc) {
      const float coef = Wl[ct * 32 + cc][n];
      if (coef != 0.f) {
        const float* wp = &wvs[cc][dq * 16];
        #pragma unroll
        for (int i4 = 0; i4 < 4; ++i4) {
          f4v wq = *(const f4v*)(wp + i4 * 4);
          acc[i4 * 4 + 0] += coef * wq[0];
          acc[i4 * 4 + 1] += coef * wq[1];
          acc[i4 * 4 + 2] += coef * wq[2];
          acc[i4 * 4 + 3] += coef * wq[3];
        }
      }
    }
  }

  float s1 = 0.f;
  #pragma unroll
  for (int i = 0; i < 16; ++i) s1 += acc[i];
  #pragma unroll
  for (int m = 1; m < 16; m <<= 1) s1 += __shfl_xor(s1, m);
  const float mean = s1 * (1.0f / 256.0f);
  float s2 = 0.f;
  #pragma unroll
  for (int i = 0; i < 16; ++i) { float dd = acc[i] - mean; s2 += dd * dd; }
  #pragma unroll
  for (int m = 1; m < 16; m <<= 1) s2 += __shfl_xor(s2, m);
  const float rstd = rsqrtf(s2 * (1.0f / 256.0f) + 1e-5f);
  {
    const int base = (bb * 64 + n) * 256 + dq * 16;
    #pragma unroll
    for (int i = 0; i < 16; ++i) {
      int dd = dq * 16 + i;
      outns[base + i] = (acc[i] - mean) * rstd * lnss[dd] + lnsb[dd];
    }
  }
}

// ---------------- GEMM2: full global_load_lds staging ----------------
__global__ __launch_bounds__(512, 2) void k_gemm2(const unsigned short* __restrict__ a,
    const unsigned short* __restrict__ wot, float* __restrict__ out)
{
  __shared__ unsigned short As[128 * 64];
  __shared__ unsigned short Bs[256 * 64];
  const int tid = threadIdx.x;
  const int w = tid >> 6, lane = tid & 63;
  const int wm = w >> 2, wn = w & 3;
  const int mblk = blockIdx.x >> 2, nblk = blockIdx.x & 3;
  const int row0 = mblk * 128, n0 = nblk * 256;
  f4v zz = {0.f, 0.f, 0.f, 0.f};
  f4v acc[4][4];
  #pragma unroll
  for (int i = 0; i < 4; ++i)
    #pragma unroll
    for (int j = 0; j < 4; ++j) acc[i][j] = zz;
  const int grow = w * 8 + (lane >> 3);
  const int gswz = ((lane & 7) ^ (lane >> 3)) << 3;
  for (int kt = 0; kt < 4; ++kt) {
    const int k0 = kt * 64;
    gload16(a + (size_t)(row0 + grow) * 256 + k0 + gswz,        &As[w * 512]);
    gload16(a + (size_t)(row0 + 64 + grow) * 256 + k0 + gswz,   &As[4096 + w * 512]);
    #pragma unroll
    for (int i = 0; i < 4; ++i)
      gload16(wot + (size_t)(n0 + i * 64 + grow) * 256 + k0 + gswz, &Bs[i * 4096 + w * 512]);
    __syncthreads();
    #pragma unroll
    for (int kk = 0; kk < 64; kk += 32) {
      const int kb = kk + (lane >> 4) * 8;
      s8v af[4], bf[4];
      #pragma unroll
      for (int mi = 0; mi < 4; ++mi) {
        const int r = wm * 64 + mi * 16 + (lane & 15);
        af[mi] = *(const s8v*)&As[r * 64 + (kb ^ ((r & 7) * 8))];
      }
      #pragma unroll
      for (int ni = 0; ni < 4; ++ni) {
        const int r = wn * 64 + ni * 16 + (lane & 15);
        bf[ni] = *(const s8v*)&Bs[r * 64 + (kb ^ ((r & 7) * 8))];
      }
      #pragma unroll
      for (int mi = 0; mi < 4; ++mi)
        #pragma unroll
        for (int ni = 0; ni < 4; ++ni)
          acc[mi][ni] = __builtin_amdgcn_mfma_f32_16x16x32_bf16(af[mi], bf[ni], acc[mi][ni], 0, 0, 0);
    }
    __syncthreads();
  }
  #pragma unroll
  for (int mi = 0; mi < 4; ++mi)
    #pragma unroll
    for (int j = 0; j < 4; ++j) {
      const int r = row0 + wm * 64 + mi * 16 + (lane >> 4) * 4 + j;
      #pragma unroll
      for (int ni = 0; ni < 4; ++ni) {
        const int cidx = wn * 64 + ni * 16 + (lane & 15);
        out[(size_t)r * 1024 + n0 + cidx] = acc[mi][ni][j];
      }
    }
}

extern "C" void kernel_launch(void* const* d_in, const int* in_sizes, int n_in,
                              void* d_out, int out_size, void* d_ws, size_t ws_size,
                              hipStream_t stream) {
  const float* x      = (const float*)d_in[0];
  const float* smem   = (const float*)d_in[1];
  const float* skeys  = (const float*)d_in[2];
  const float* W_in   = (const float*)d_in[3];
  const float* W_wr   = (const float*)d_in[4];
  const float* wgate  = (const float*)d_in[5];
  const float* bgate  = (const float*)d_in[6];
  const float* W_out  = (const float*)d_in[7];
  const float* lnis   = (const float*)d_in[8];
  const float* lnib   = (const float*)d_in[9];
  const float* lnss   = (const float*)d_in[10];
  const float* lnsb   = (const float*)d_in[11];
  (void)in_sizes; (void)n_in; (void)out_size; (void)ws_size;

  char* ws = (char*)d_ws;
  float*          q_buf = (float*)(ws + 0);                       // 134217728
  unsigned short* readb = (unsigned short*)(ws + 134217728);      // 16777216
  float*          summ  = (float*)(ws + 150994944);               // 2097152
  float*          wv    = (float*)(ws + 153092096);               // 2097152
  unsigned short* wth   = (unsigned short*)(ws + 155189248);      // 524288
  unsigned short* wtl   = (unsigned short*)(ws + 155713536);      // 524288
  unsigned short* wot   = (unsigned short*)(ws + 156237824);      // 524288
  float*          keyn  = (float*)(ws + 156762112);               // 65536
  float*          uvec  = (float*)(ws + 157089792);               // 1024
  float*          vvec  = (float*)(ws + 157090816);               // 1024
  float*          d0    = (float*)(ws + 157091840);               // 256
  int*            top3  = (int*)(ws + 157092096);                 // 32768
  float*          wg2   = (float*)(ws + 157124864);               // 8192
  float*          dwv   = (float*)(ws + 157133056);               // 8192

  float* out   = (float*)d_out;
  float* outns = out + 33554432;

  k_prep<<<dim3(2113), dim3(256), 0, stream>>>(W_in, lnis, lnib, W_out, skeys, smem, wgate,
                                               wth, wtl, wot, keyn, d0, uvec, vvec);
  k_gemm1<<<dim3(512), dim3(512), 0, stream>>>(x, wth, wtl, uvec, vvec, q_buf);
  k_attn<<<dim3(512), dim3(512), 0, stream>>>(q_buf, smem, readb, summ);
  k_match<<<dim3(256), dim3(256), 0, stream>>>(summ, keyn, W_wr, wgate, top3, wv, wg2, dwv);
  k_scan<<<dim3(8), dim3(1024), 0, stream>>>(d0, top3, wg2, dwv, bgate, wv, smem, lnss, lnsb, outns);
  k_gemm2<<<dim3(1024), dim3(512), 0, stream>>>(readb, wot, out);
}

// Round 21
// 287.678 us; speedup vs baseline: 1.1478x; 1.1478x over previous
//
#include <hip/hip_runtime.h>

typedef __attribute__((ext_vector_type(8))) short s8v;
typedef __attribute__((ext_vector_type(4))) float f4v;

#define PADG 72

union U8 { unsigned u[4]; s8v s; };

__device__ __forceinline__ void gload16(const void* g, void* l) {
  __builtin_amdgcn_global_load_lds((const __attribute__((address_space(1))) void*)g,
                                   (__attribute__((address_space(3))) void*)l, 16, 0, 0);
}

__device__ __forceinline__ unsigned short f2bf(float f) {
  unsigned u = __float_as_uint(f);
  u += 0x7fffu + ((u >> 16) & 1u);
  return (unsigned short)(u >> 16);
}
__device__ __forceinline__ unsigned short f2bfc(float f) {
  return (unsigned short)((__float_as_uint(f) + 0x8000u) >> 16);
}
__device__ __forceinline__ float bf2f(unsigned short h) {
  return __uint_as_float(((unsigned)h) << 16);
}
__device__ __forceinline__ void split2(float x0, float x1, unsigned& hp, unsigned& lp) {
  unsigned t0 = __float_as_uint(x0) + 0x8000u;
  unsigned t1 = __float_as_uint(x1) + 0x8000u;
  float h0 = __uint_as_float(t0 & 0xFFFF0000u);
  float h1 = __uint_as_float(t1 & 0xFFFF0000u);
  float l0 = x0 - h0, l1 = x1 - h1;
  hp = __builtin_amdgcn_perm(t1, t0, 0x07060302u);
  lp = __builtin_amdgcn_perm(__float_as_uint(l1) + 0x8000u,
                             __float_as_uint(l0) + 0x8000u, 0x07060302u);
}
__device__ __forceinline__ unsigned pack2(float a, float b) {
  return __builtin_amdgcn_perm(__float_as_uint(b) + 0x8000u,
                               __float_as_uint(a) + 0x8000u, 0x07060302u);
}
__device__ __forceinline__ f4v vmax4(f4v a, f4v b) {
  f4v r; r[0]=fmaxf(a[0],b[0]); r[1]=fmaxf(a[1],b[1]); r[2]=fmaxf(a[2],b[2]); r[3]=fmaxf(a[3],b[3]); return r;
}
__device__ __forceinline__ f4v shflxor4(f4v v, int m) {
  f4v r; r[0]=__shfl_xor(v[0],m); r[1]=__shfl_xor(v[1],m); r[2]=__shfl_xor(v[2],m); r[3]=__shfl_xor(v[3],m); return r;
}
__device__ __forceinline__ f4v exp4(f4v v) {
  f4v r; r[0]=__expf(v[0]); r[1]=__expf(v[1]); r[2]=__expf(v[2]); r[3]=__expf(v[3]); return r;
}

// ---------------- prep ----------------
__global__ void k_prep(const float* __restrict__ W_in, const float* __restrict__ lnis,
                       const float* __restrict__ lnib, const float* __restrict__ W_out,
                       const float* __restrict__ skeys, const float* __restrict__ smem0,
                       const float* __restrict__ wgate,
                       unsigned short* __restrict__ wth, unsigned short* __restrict__ wtl,
                       unsigned short* __restrict__ wot, float* __restrict__ keyn,
                       float* __restrict__ d0, float* __restrict__ uvec, float* __restrict__ vvec)
{
  __shared__ float pr[4];
  const int bid = blockIdx.x, tid = threadIdx.x;
  if (bid < 1024) {
    int idx = bid * 256 + tid;           // wt layout [n=256][k=1024]
    int n = idx >> 10, k = idx & 1023;
    float val = lnis[k] * W_in[k * 256 + n];
    unsigned short h = f2bf(val);
    wth[idx] = h;
    wtl[idx] = f2bf(val - bf2f(h));
  } else if (bid < 2048) {
    int idx = (bid - 1024) * 256 + tid;  // wot layout [n=1024][k=256]
    int n = idx >> 8, k = idx & 255;
    wot[idx] = f2bf(W_out[k * 1024 + n]);
  } else if (bid == 2048) {
    float su = 0.f, sv = 0.f;
    for (int i = 0; i < 1024; ++i) {
      float wv_ = W_in[i * 256 + tid];
      su += lnis[i] * wv_;
      sv += lnib[i] * wv_;
    }
    uvec[tid] = su; vvec[tid] = sv;
  } else {
    int n = bid - 2049;
    float sk = skeys[n * 256 + tid];
    float sq = sk * sk;
    #pragma unroll
    for (int m = 32; m; m >>= 1) sq += __shfl_xor(sq, m);
    if ((tid & 63) == 0) pr[tid >> 6] = sq;
    __syncthreads();
    float tot = pr[0] + pr[1] + pr[2] + pr[3];
    keyn[n * 256 + tid] = sk * (1.0f / fmaxf(sqrtf(tot), 1e-12f));
    float pd = smem0[n * 256 + tid] * wgate[tid];
    #pragma unroll
    for (int m = 32; m; m >>= 1) pd += __shfl_xor(pd, m);
    __syncthreads();
    if ((tid & 63) == 0) pr[tid >> 6] = pd;
    __syncthreads();
    if (tid == 0) d0[n] = pr[0] + pr[1] + pr[2] + pr[3];
  }
}

// ---------------- GEMM1: XCD-aware mapping, split-bf16 ----------------
__global__ __launch_bounds__(512, 4) void k_gemm1(const float* __restrict__ x,
    const unsigned short* __restrict__ wth, const unsigned short* __restrict__ wtl,
    const float* __restrict__ uvec, const float* __restrict__ vvec,
    float* __restrict__ q)
{
  __shared__ unsigned short Ah[128 * PADG], Al[128 * PADG];
  __shared__ unsigned short Bh[128 * PADG], Bl[128 * PADG];
  __shared__ float uls[128], vls[128];
  __shared__ float mls[128], rls[128];
  const int tid = threadIdx.x;
  const int w = tid >> 6, lane = tid & 63;
  const int wm = w >> 2, wn = w & 3;
  const int bid = blockIdx.x;
  const int mblk = (bid >> 4) * 8 + (bid & 7), nblk = (bid >> 3) & 1;
  const int row0 = mblk * 128, n0 = nblk * 128;
  if (tid < 128) { uls[tid] = uvec[n0 + tid]; vls[tid] = vvec[n0 + tid]; }
  f4v zz = {0.f, 0.f, 0.f, 0.f};
  f4v acc[4][2];
  #pragma unroll
  for (int i = 0; i < 4; ++i)
    #pragma unroll
    for (int j = 0; j < 2; ++j) acc[i][j] = zz;
  const int rowA = tid >> 2, kqA = (tid & 3) * 16;
  float ps = 0.f, pss = 0.f;
  for (int kt = 0; kt < 16; ++kt) {
    const int k0 = kt * 64;
    {
      const float* src = x + (size_t)(row0 + rowA) * 1024 + k0 + kqA;
      float vv[16];
      #pragma unroll
      for (int i = 0; i < 4; ++i) *(f4v*)(vv + 4 * i) = *(const f4v*)(src + 4 * i);
      unsigned hp[8], lp[8];
      #pragma unroll
      for (int i = 0; i < 8; ++i) {
        ps += vv[2 * i] + vv[2 * i + 1];
        pss += vv[2 * i] * vv[2 * i] + vv[2 * i + 1] * vv[2 * i + 1];
        split2(vv[2 * i], vv[2 * i + 1], hp[i], lp[i]);
      }
      uint4* dh = (uint4*)&Ah[rowA * PADG + kqA];
      uint4* dl = (uint4*)&Al[rowA * PADG + kqA];
      dh[0] = make_uint4(hp[0], hp[1], hp[2], hp[3]);
      dh[1] = make_uint4(hp[4], hp[5], hp[6], hp[7]);
      dl[0] = make_uint4(lp[0], lp[1], lp[2], lp[3]);
      dl[1] = make_uint4(lp[4], lp[5], lp[6], lp[7]);
      const unsigned short* sh = wth + (size_t)(n0 + rowA) * 1024 + k0 + kqA;
      const unsigned short* sl = wtl + (size_t)(n0 + rowA) * 1024 + k0 + kqA;
      *(s8v*)&Bh[rowA * PADG + kqA] = *(const s8v*)sh;
      *(s8v*)&Bh[rowA * PADG + kqA + 8] = *(const s8v*)(sh + 8);
      *(s8v*)&Bl[rowA * PADG + kqA] = *(const s8v*)sl;
      *(s8v*)&Bl[rowA * PADG + kqA + 8] = *(const s8v*)(sl + 8);
    }
    __syncthreads();
    #pragma unroll
    for (int kk = 0; kk < 64; kk += 32) {
      const int kb = kk + (lane >> 4) * 8;
      s8v ah[4], al[4], bh[2], bl[2];
      #pragma unroll
      for (int mi = 0; mi < 4; ++mi) {
        const int rr = (wm * 64 + mi * 16 + (lane & 15)) * PADG + kb;
        ah[mi] = *(const s8v*)&Ah[rr];
        al[mi] = *(const s8v*)&Al[rr];
      }
      #pragma unroll
      for (int ni = 0; ni < 2; ++ni) {
        const int ccv = (wn * 32 + ni * 16 + (lane & 15)) * PADG + kb;
        bh[ni] = *(const s8v*)&Bh[ccv];
        bl[ni] = *(const s8v*)&Bl[ccv];
      }
      #pragma unroll
      for (int mi = 0; mi < 4; ++mi)
        #pragma unroll
        for (int ni = 0; ni < 2; ++ni) {
          acc[mi][ni] = __builtin_amdgcn_mfma_f32_16x16x32_bf16(ah[mi], bh[ni], acc[mi][ni], 0, 0, 0);
          acc[mi][ni] = __builtin_amdgcn_mfma_f32_16x16x32_bf16(ah[mi], bl[ni], acc[mi][ni], 0, 0, 0);
          acc[mi][ni] = __builtin_amdgcn_mfma_f32_16x16x32_bf16(al[mi], bh[ni], acc[mi][ni], 0, 0, 0);
        }
    }
    __syncthreads();
  }
  {
    float s0 = ps, s1 = pss;
    s0 += __shfl_xor(s0, 1); s1 += __shfl_xor(s1, 1);
    s0 += __shfl_xor(s0, 2); s1 += __shfl_xor(s1, 2);
    if ((tid & 3) == 0) {
      float mean = s0 * (1.0f / 1024.0f);
      mls[rowA] = mean;
      rls[rowA] = rsqrtf(s1 * (1.0f / 1024.0f) - mean * mean + 1e-5f);
    }
  }
  __syncthreads();
  #pragma unroll
  for (int mi = 0; mi < 4; ++mi)
    #pragma unroll
    for (int j = 0; j < 4; ++j) {
      const int lr = wm * 64 + mi * 16 + (lane >> 4) * 4 + j;
      const int r = row0 + lr;
      const float mv = mls[lr], rv = rls[lr];
      #pragma unroll
      for (int ni = 0; ni < 2; ++ni) {
        const int lc = wn * 32 + ni * 16 + (lane & 15);
        q[(size_t)r * 256 + n0 + lc] = rv * acc[mi][ni][j] - rv * mv * uls[lc] + vls[lc];
      }
    }
}

// ---------------- attention via MFMA, Kf LDS-staged, 8 chunks/block ----------------
__global__ __launch_bounds__(512, 2) void k_attn(const float* __restrict__ q,
    const float* __restrict__ smem0, unsigned short* __restrict__ readb,
    float* __restrict__ summ)
{
  __shared__ float Kf[64 * 256];
  __shared__ float Pl[8][16 * 68];
  __shared__ float csm[8][64];
  const int tid = threadIdx.x;
  const int w = tid >> 6, lane = tid & 63;
  const int h = w & 3;
  const int l15 = lane & 15, kq = lane >> 4;

  {
    const int base = tid * 32;
    #pragma unroll
    for (int i = 0; i < 8; ++i)
      *(f4v*)&Kf[base + i * 4] = *(const f4v*)&smem0[base + i * 4];
  }
  __syncthreads();

  s8v bsh[4][2], bsl[4][2], bpv[4][2];
  #pragma unroll
  for (int nt = 0; nt < 4; ++nt)
    #pragma unroll
    for (int ks = 0; ks < 2; ++ks) {
      const float* src = &Kf[(nt * 16 + l15) * 256 + h * 64 + ks * 32 + kq * 8];
      float tmp[8];
      *(f4v*)tmp = *(const f4v*)src; *(f4v*)(tmp + 4) = *(const f4v*)(src + 4);
      U8 uh, ul;
      #pragma unroll
      for (int j = 0; j < 4; ++j) split2(tmp[2 * j], tmp[2 * j + 1], uh.u[j], ul.u[j]);
      bsh[nt][ks] = uh.s;
      bsl[nt][ks] = ul.s;
      U8 up;
      #pragma unroll
      for (int j = 0; j < 4; ++j)
        up.u[j] = pack2(Kf[(ks * 32 + kq * 8 + 2 * j) * 256 + h * 64 + nt * 16 + l15],
                        Kf[(ks * 32 + kq * 8 + 2 * j + 1) * 256 + h * 64 + nt * 16 + l15]);
      bpv[nt][ks] = up.s;
    }

  const int g0 = blockIdx.x * 8 + (w >> 2) * 4;
  f4v qv[2][4];
  {
    #pragma unroll
    for (int ks = 0; ks < 2; ++ks) {
      const float* qp = q + (size_t)(g0 * 16 + l15) * 256 + h * 64 + ks * 32 + kq * 8;
      qv[0][ks * 2] = *(const f4v*)qp;
      qv[0][ks * 2 + 1] = *(const f4v*)(qp + 4);
    }
  }
  #pragma unroll
  for (int i = 0; i < 4; ++i) {
    const int cur = i & 1, nxt = cur ^ 1;
    if (i < 3) {
      const int gn = g0 + i + 1;
      #pragma unroll
      for (int ks = 0; ks < 2; ++ks) {
        const float* qp = q + (size_t)(gn * 16 + l15) * 256 + h * 64 + ks * 32 + kq * 8;
        qv[nxt][ks * 2] = *(const f4v*)qp;
        qv[nxt][ks * 2 + 1] = *(const f4v*)(qp + 4);
      }
    }
    const int g = g0 + i;
    s8v ah[2], al[2];
    #pragma unroll
    for (int ks = 0; ks < 2; ++ks) {
      float tmp[8];
      *(f4v*)tmp = qv[cur][ks * 2]; *(f4v*)(tmp + 4) = qv[cur][ks * 2 + 1];
      U8 uh, ul;
      #pragma unroll
      for (int j = 0; j < 4; ++j) split2(tmp[2 * j], tmp[2 * j + 1], uh.u[j], ul.u[j]);
      ah[ks] = uh.s; al[ks] = ul.s;
    }
    f4v zz = {0.f, 0.f, 0.f, 0.f};
    f4v sacc[4] = {zz, zz, zz, zz};
    #pragma unroll
    for (int ks = 0; ks < 2; ++ks)
      #pragma unroll
      for (int nt = 0; nt < 4; ++nt) {
        sacc[nt] = __builtin_amdgcn_mfma_f32_16x16x32_bf16(ah[ks], bsh[nt][ks], sacc[nt], 0, 0, 0);
        sacc[nt] = __builtin_amdgcn_mfma_f32_16x16x32_bf16(ah[ks], bsl[nt][ks], sacc[nt], 0, 0, 0);
        sacc[nt] = __builtin_amdgcn_mfma_f32_16x16x32_bf16(al[ks], bsh[nt][ks], sacc[nt], 0, 0, 0);
      }
    #pragma unroll
    for (int nt = 0; nt < 4; ++nt) sacc[nt] = sacc[nt] * 0.125f;
    f4v mx = vmax4(vmax4(sacc[0], sacc[1]), vmax4(sacc[2], sacc[3]));
    #pragma unroll
    for (int m = 1; m <= 8; m <<= 1) mx = vmax4(mx, shflxor4(mx, m));
    f4v p[4];
    f4v psum = zz;
    #pragma unroll
    for (int nt = 0; nt < 4; ++nt) { p[nt] = exp4(sacc[nt] - mx); psum = psum + p[nt]; }
    #pragma unroll
    for (int m = 1; m <= 8; m <<= 1) psum = psum + shflxor4(psum, m);
    f4v rs;
    rs[0] = 1.0f / psum[0]; rs[1] = 1.0f / psum[1];
    rs[2] = 1.0f / psum[2]; rs[3] = 1.0f / psum[3];
    #pragma unroll
    for (int nt = 0; nt < 4; ++nt) p[nt] = p[nt] * rs;
    float cs4[4];
    #pragma unroll
    for (int nt = 0; nt < 4; ++nt) {
      cs4[nt] = p[nt][0] + p[nt][1] + p[nt][2] + p[nt][3];
      cs4[nt] += __shfl_xor(cs4[nt], 16);
      cs4[nt] += __shfl_xor(cs4[nt], 32);
    }
    if (kq == 0) {
      #pragma unroll
      for (int nt = 0; nt < 4; ++nt) csm[w][nt * 16 + l15] = cs4[nt];
    }
    #pragma unroll
    for (int nt = 0; nt < 4; ++nt)
      #pragma unroll
      for (int j = 0; j < 4; ++j)
        Pl[w][(kq * 4 + j) * 68 + nt * 16 + l15] = p[nt][j];
    s8v pa[2];
    #pragma unroll
    for (int ks = 0; ks < 2; ++ks) {
      const float* pp = &Pl[w][l15 * 68 + ks * 32 + kq * 8];
      float tmp[8];
      *(f4v*)tmp = *(const f4v*)pp; *(f4v*)(tmp + 4) = *(const f4v*)(pp + 4);
      U8 up;
      #pragma unroll
      for (int j = 0; j < 4; ++j) up.u[j] = pack2(tmp[2 * j], tmp[2 * j + 1]);
      pa[ks] = up.s;
    }
    f4v racc[4] = {zz, zz, zz, zz};
    #pragma unroll
    for (int ks = 0; ks < 2; ++ks)
      #pragma unroll
      for (int nt = 0; nt < 4; ++nt)
        racc[nt] = __builtin_amdgcn_mfma_f32_16x16x32_bf16(pa[ks], bpv[nt][ks], racc[nt], 0, 0, 0);
    const int rowbase = (g >> 8) * 4096 + (g & 255) * 16;
    #pragma unroll
    for (int nt = 0; nt < 4; ++nt)
      #pragma unroll
      for (int j = 0; j < 4; ++j)
        readb[(size_t)(rowbase + kq * 4 + j) * 256 + h * 64 + nt * 16 + l15] = f2bfc(racc[nt][j]);
    float s = 0.f;
    #pragma unroll 8
    for (int n = 0; n < 64; ++n) s += csm[w][n] * Kf[n * 256 + h * 64 + lane];
    summ[(size_t)g * 256 + h * 64 + lane] = s * (1.0f / 16.0f);
  }
}

// ---------------- per-chunk: 8 chunks/block ----------------
__global__ void k_match(const float* __restrict__ summ, const float* __restrict__ keyn,
                        const float* __restrict__ Wwr, const float* __restrict__ wgate,
                        int* __restrict__ top3, float* __restrict__ wv,
                        float* __restrict__ wg2, float* __restrict__ dwv)
{
  __shared__ float sm[8][256];
  __shared__ float nrm_inv[8];
  __shared__ float mtch[8][64];
  __shared__ float redA[8][4], redB[8][4];
  const int tid = threadIdx.x, lane = tid & 63, w = tid >> 6;
  const int gbase = blockIdx.x * 8;
  #pragma unroll
  for (int gi = 0; gi < 8; ++gi) sm[gi][tid] = summ[(size_t)(gbase + gi) * 256 + tid];
  __syncthreads();
  {
    #pragma unroll
    for (int pass = 0; pass < 2; ++pass) {
      const int gi = w + pass * 4;
      float ss = 0.f;
      #pragma unroll
      for (int i = 0; i < 4; ++i) { float vv_ = sm[gi][lane + i * 64]; ss += vv_ * vv_; }
      #pragma unroll
      for (int m = 32; m; m >>= 1) ss += __shfl_xor(ss, m);
      if (lane == 0) nrm_inv[gi] = 1.0f / fmaxf(sqrtf(ss), 1e-12f);
    }
  }
  __syncthreads();
  {
    const int n = tid >> 2, qq = tid & 3;
    float mac[8] = {0.f, 0.f, 0.f, 0.f, 0.f, 0.f, 0.f, 0.f};
    const float* kp = keyn + n * 256 + qq * 64;
    for (int d = 0; d < 64; ++d) {
      float kv = kp[d];
      int dd = qq * 64 + d;
      #pragma unroll
      for (int gi = 0; gi < 8; ++gi) mac[gi] += sm[gi][dd] * kv;
    }
    #pragma unroll
    for (int gi = 0; gi < 8; ++gi) {
      float v2_ = mac[gi];
      v2_ += __shfl_xor(v2_, 1);
      v2_ += __shfl_xor(v2_, 2);
      if (qq == 0) mtch[gi][n] = v2_ * nrm_inv[gi];
    }
  }
  __syncthreads();
  {
    #pragma unroll
    for (int pass = 0; pass < 2; ++pass) {
      const int gi = w + pass * 4;
      float vorig = mtch[gi][lane];
      #pragma unroll
      for (int it = 0; it < 3; ++it) {
        float rv = vorig; int ri = lane;
        #pragma unroll
        for (int m = 32; m; m >>= 1) {
          float ov = __shfl_xor(rv, m); int oi = __shfl_xor(ri, m);
          if (ov > rv || (ov == rv && oi < ri)) { rv = ov; ri = oi; }
        }
        if (lane == 0) top3[(gbase + gi) * 4 + it] = ri;
        if (lane == ri) vorig = -3.0e38f;
      }
    }
  }
  float wva[8] = {0.f, 0.f, 0.f, 0.f, 0.f, 0.f, 0.f, 0.f};
  for (int d = 0; d < 256; ++d) {
    float ww = Wwr[(size_t)d * 256 + tid];
    #pragma unroll
    for (int gi = 0; gi < 8; ++gi) wva[gi] += sm[gi][d] * ww;
  }
  const float g1 = wgate[tid], g2 = wgate[256 + tid];
  #pragma unroll
  for (int gi = 0; gi < 8; ++gi) {
    wv[(size_t)(gbase + gi) * 256 + tid] = wva[gi];
    float p2 = wva[gi] * g2, p1 = wva[gi] * g1;
    #pragma unroll
    for (int m = 32; m; m >>= 1) { p2 += __shfl_xor(p2, m); p1 += __shfl_xor(p1, m); }
    if (lane == 0) { redA[gi][w] = p2; redB[gi][w] = p1; }
  }
  __syncthreads();
  if (tid < 8) {
    wg2[gbase + tid] = redA[tid][0] + redA[tid][1] + redA[tid][2] + redA[tid][3];
    dwv[gbase + tid] = redB[tid][0] + redB[tid][1] + redB[tid][2] + redB[tid][3];
  }
}

// ---------------- scan: single-lane LDS-resident gate chain ----------------
__global__ __launch_bounds__(1024) void k_scan(const float* __restrict__ d0,
    const int* __restrict__ top3, const float* __restrict__ wg2, const float* __restrict__ dwv,
    const float* __restrict__ bgate, const float* __restrict__ wv,
    const float* __restrict__ smem0, const float* __restrict__ lnss,
    const float* __restrict__ lnsb, float* __restrict__ outns)
{
  __shared__ float Wl[256][64];
  __shared__ float pn[64];
  __shared__ float wvs[32][256];
  __shared__ float gls[256];
  __shared__ int   pprm[256][4];
  __shared__ float dsl[64];
  const int bb = blockIdx.x, tid = threadIdx.x;
  const int lane = tid & 63;

  int ixA[4], iyA[4], izA[4];
  if (tid < 64) {
    const float bg = bgate[0];
    const float L2E = 1.4426950408889634f;
    #pragma unroll
    for (int j = 0; j < 4; ++j) {
      const int c = j * 64 + tid;
      int4 t3 = *(const int4*)&top3[(bb * 256 + c) * 4];
      ixA[j] = t3.x; iyA[j] = t3.y; izA[j] = t3.z;
      pprm[c][0] = t3.x | (t3.y << 6) | (t3.z << 12);
      pprm[c][1] = __float_as_int(-(wg2[bb * 256 + c] + bg) * L2E);
      pprm[c][2] = __float_as_int(dwv[bb * 256 + c]);
      pprm[c][3] = 0;
    }
    dsl[tid] = d0[tid];
  }
  __syncthreads();

  if (tid == 0) {
    const float COEFN = -0.48089834696298783f;
    #pragma unroll 2
    for (int c = 0; c < 256; ++c) {
      const int4 pr = *(const int4*)&pprm[c][0];
      const int i0 = pr.x & 63, i1 = (pr.x >> 6) & 63, i2 = (pr.x >> 12) & 63;
      const float wz = __int_as_float(pr.y);
      const float dv = __int_as_float(pr.z);
      const float a = dsl[i0], b = dsl[i1], d2 = dsl[i2];
      const float s3 = a + b + d2;
      const float e = __builtin_amdgcn_exp2f(fmaf(s3, COEFN, wz));
      const float g = __builtin_amdgcn_rcpf(1.0f + e);
      gls[c] = g;
      dsl[i0] = fmaf(g, dv - a, a);
      dsl[i1] = fmaf(g, dv - b, b);
      dsl[i2] = fmaf(g, dv - d2, d2);
    }
  }
  __syncthreads();

  if (tid < 64) {
    float running = 1.0f;
    #pragma unroll
    for (int j = 3; j >= 0; --j) {
      #pragma unroll 1
      for (int sl = 63; sl >= 0; --sl) {
        const int a0 = __builtin_amdgcn_readlane(ixA[j], sl);
        const int a1 = __builtin_amdgcn_readlane(iyA[j], sl);
        const int a2 = __builtin_amdgcn_readlane(izA[j], sl);
        const float gv = gls[j * 64 + sl];
        const bool hit = (lane == a0) | (lane == a1) | (lane == a2);
        Wl[j * 64 + sl][lane] = hit ? gv * running : 0.f;
        running = hit ? running * (1.0f - gv) : running;
      }
    }
    pn[lane] = running;
  }
  __syncthreads();

  const int n = tid >> 4, dq = tid & 15;
  float acc[16];
  {
    const float p = pn[n];
    const float* v0p = smem0 + n * 256 + dq * 16;
    #pragma unroll
    for (int i = 0; i < 16; i += 4) {
      f4v v0 = *(const f4v*)(v0p + i);
      acc[i] = p * v0[0]; acc[i + 1] = p * v0[1];
      acc[i + 2] = p * v0[2]; acc[i + 3] = p * v0[3];
    }
  }
  const int rr = tid >> 5, cc8 = (tid & 31) * 8;
  for (int ct = 0; ct < 8; ++ct) {
    __syncthreads();
    {
      const float* src = wv + (size_t)(bb * 256 + ct * 32 + rr) * 256 + cc8;
      *(f4v*)&wvs[rr][cc8] = *(const f4v*)src;
      *(f4v*)&wvs[rr][cc8 + 4] = *(const f4v*)(src + 4);
    }
    __syncthreads();
    #pragma unroll 1
    for (int cc = 0; cc < 32; ++cc) {
      const float coef = Wl[ct * 32 + cc][n];
      if (coef != 0.f) {
        const float* wp = &wvs[cc][dq * 16];
        #pragma unroll
        for (int i4 = 0; i4 < 4; ++i4) {
          f4v wq = *(const f4v*)(wp + i4 * 4);
          acc[i4 * 4 + 0] += coef * wq[0];
          acc[i4 * 4 + 1] += coef * wq[1];
          acc[i4 * 4 + 2] += coef * wq[2];
          acc[i4 * 4 + 3] += coef * wq[3];
        }
      }
    }
  }

  float s1 = 0.f;
  #pragma unroll
  for (int i = 0; i < 16; ++i) s1 += acc[i];
  #pragma unroll
  for (int m = 1; m < 16; m <<= 1) s1 += __shfl_xor(s1, m);
  const float mean = s1 * (1.0f / 256.0f);
  float s2 = 0.f;
  #pragma unroll
  for (int i = 0; i < 16; ++i) { float dd = acc[i] - mean; s2 += dd * dd; }
  #pragma unroll
  for (int m = 1; m < 16; m <<= 1) s2 += __shfl_xor(s2, m);
  const float rstd = rsqrtf(s2 * (1.0f / 256.0f) + 1e-5f);
  {
    const int base = (bb * 64 + n) * 256 + dq * 16;
    #pragma unroll
    for (int i = 0; i < 16; ++i) {
      int dd = dq * 16 + i;
      outns[base + i] = (acc[i] - mean) * rstd * lnss[dd] + lnsb[dd];
    }
  }
}

// ---------------- GEMM2: full global_load_lds staging ----------------
__global__ __launch_bounds__(512, 2) void k_gemm2(const unsigned short* __restrict__ a,
    const unsigned short* __restrict__ wot, float* __restrict__ out)
{
  __shared__ unsigned short As[128 * 64];
  __shared__ unsigned short Bs[256 * 64];
  const int tid = threadIdx.x;
  const int w = tid >> 6, lane = tid & 63;
  const int wm = w >> 2, wn = w & 3;
  const int mblk = blockIdx.x >> 2, nblk = blockIdx.x & 3;
  const int row0 = mblk * 128, n0 = nblk * 256;
  f4v zz = {0.f, 0.f, 0.f, 0.f};
  f4v acc[4][4];
  #pragma unroll
  for (int i = 0; i < 4; ++i)
    #pragma unroll
    for (int j = 0; j < 4; ++j) acc[i][j] = zz;
  const int grow = w * 8 + (lane >> 3);
  const int gswz = ((lane & 7) ^ (lane >> 3)) << 3;
  for (int kt = 0; kt < 4; ++kt) {
    const int k0 = kt * 64;
    gload16(a + (size_t)(row0 + grow) * 256 + k0 + gswz,        &As[w * 512]);
    gload16(a + (size_t)(row0 + 64 + grow) * 256 + k0 + gswz,   &As[4096 + w * 512]);
    #pragma unroll
    for (int i = 0; i < 4; ++i)
      gload16(wot + (size_t)(n0 + i * 64 + grow) * 256 + k0 + gswz, &Bs[i * 4096 + w * 512]);
    __syncthreads();
    #pragma unroll
    for (int kk = 0; kk < 64; kk += 32) {
      const int kb = kk + (lane >> 4) * 8;
      s8v af[4], bf[4];
      #pragma unroll
      for (int mi = 0; mi < 4; ++mi) {
        const int r = wm * 64 + mi * 16 + (lane & 15);
        af[mi] = *(const s8v*)&As[r * 64 + (kb ^ ((r & 7) * 8))];
      }
      #pragma unroll
      for (int ni = 0; ni < 4; ++ni) {
        const int r = wn * 64 + ni * 16 + (lane & 15);
        bf[ni] = *(const s8v*)&Bs[r * 64 + (kb ^ ((r & 7) * 8))];
      }
      #pragma unroll
      for (int mi = 0; mi < 4; ++mi)
        #pragma unroll
        for (int ni = 0; ni < 4; ++ni)
          acc[mi][ni] = __builtin_amdgcn_mfma_f32_16x16x32_bf16(af[mi], bf[ni], acc[mi][ni], 0, 0, 0);
    }
    __syncthreads();
  }
  #pragma unroll
  for (int mi = 0; mi < 4; ++mi)
    #pragma unroll
    for (int j = 0; j < 4; ++j) {
      const int r = row0 + wm * 64 + mi * 16 + (lane >> 4) * 4 + j;
      #pragma unroll
      for (int ni = 0; ni < 4; ++ni) {
        const int cidx = wn * 64 + ni * 16 + (lane & 15);
        out[(size_t)r * 1024 + n0 + cidx] = acc[mi][ni][j];
      }
    }
}

extern "C" void kernel_launch(void* const* d_in, const int* in_sizes, int n_in,
                              void* d_out, int out_size, void* d_ws, size_t ws_size,
                              hipStream_t stream) {
  const float* x      = (const float*)d_in[0];
  const float* smem   = (const float*)d_in[1];
  const float* skeys  = (const float*)d_in[2];
  const float* W_in   = (const float*)d_in[3];
  const float* W_wr   = (const float*)d_in[4];
  const float* wgate  = (const float*)d_in[5];
  const float* bgate  = (const float*)d_in[6];
  const float* W_out  = (const float*)d_in[7];
  const float* lnis   = (const float*)d_in[8];
  const float* lnib   = (const float*)d_in[9];
  const float* lnss   = (const float*)d_in[10];
  const float* lnsb   = (const float*)d_in[11];
  (void)in_sizes; (void)n_in; (void)out_size; (void)ws_size;

  char* ws = (char*)d_ws;
  float*          q_buf = (float*)(ws + 0);                       // 134217728
  unsigned short* readb = (unsigned short*)(ws + 134217728);      // 16777216
  float*          summ  = (float*)(ws + 150994944);               // 2097152
  float*          wv    = (float*)(ws + 153092096);               // 2097152
  unsigned short* wth   = (unsigned short*)(ws + 155189248);      // 524288
  unsigned short* wtl   = (unsigned short*)(ws + 155713536);      // 524288
  unsigned short* wot   = (unsigned short*)(ws + 156237824);      // 524288
  float*          keyn  = (float*)(ws + 156762112);               // 65536
  float*          uvec  = (float*)(ws + 157089792);               // 1024
  float*          vvec  = (float*)(ws + 157090816);               // 1024
  float*          d0    = (float*)(ws + 157091840);               // 256
  int*            top3  = (int*)(ws + 157092096);                 // 32768
  float*          wg2   = (float*)(ws + 157124864);               // 8192
  float*          dwv   = (float*)(ws + 157133056);               // 8192

  float* out   = (float*)d_out;
  float* outns = out + 33554432;

  k_prep<<<dim3(2113), dim3(256), 0, stream>>>(W_in, lnis, lnib, W_out, skeys, smem, wgate,
                                               wth, wtl, wot, keyn, d0, uvec, vvec);
  k_gemm1<<<dim3(512), dim3(512), 0, stream>>>(x, wth, wtl, uvec, vvec, q_buf);
  k_attn<<<dim3(256), dim3(512), 0, stream>>>(q_buf, smem, readb, summ);
  k_match<<<dim3(256), dim3(256), 0, stream>>>(summ, keyn, W_wr, wgate, top3, wv, wg2, dwv);
  k_scan<<<dim3(8), dim3(1024), 0, stream>>>(d0, top3, wg2, dwv, bgate, wv, smem, lnss, lnsb, outns);
  k_gemm2<<<dim3(1024), dim3(512), 0, stream>>>(readb, wot, out);
}